// Round 12
// baseline (439.176 us; speedup 1.0000x reference)
//
#include <hip/hip_runtime.h>
#include <stdint.h>

#define B_GRAPHS 256
#define NPER     512
#define EPER     4096
#define DDIM     64
#define KKEEP    1024
#define HIDDEN   256
#define CT       32          // hidden columns per tile
#define NTILE    (HIDDEN/CT) // 8 tiles
#define STR      36          // LDS row stride: 32 cols + 4 pad = 144B, 16B-aligned

typedef float v2f __attribute__((ext_vector_type(2)));

// Kernel A: one 1024-thread block per graph (R6-R9: only one workgroup is
// ever resident per CU, so all overlap must come from within the block).
// Thread (n = t&511, ch = t>>9) computes 16 of the tile's 32 columns over all
// 64 dims -- disjoint partials, 1 staging phase, 2 barriers/tile x 8 tiles =
// 16 barriers (R10 had 32; barrier drains ~3K cyc each were ~1/3 of wall).
// All FMA paths use v2f + __builtin_elementwise_fma -> v_pk_fma_f32 (2 FMA/
// instr; halves VALU issue if full-rate, neutral if half-rate).
// h is re-read per tile in 8-float chunks; asm clobber stops the compiler
// hoisting 64 floats into registers (R1/R3 trap: RA hard-caps 1024-thread
// kernels at 64 arch VGPRs and spills ~800MB to scratch).
__global__ __launch_bounds__(1024) void scores_kernel(
    const float* __restrict__ h, const float* __restrict__ W1,
    const float* __restrict__ b1, const float* __restrict__ W2,
    const float* __restrict__ b2, const int* __restrict__ edge0,
    const int* __restrict__ edge1, float* __restrict__ sc_out)
{
  __shared__ __align__(16) float At[NPER * STR];   // 72 KB
  __shared__ __align__(16) float Bt[NPER * STR];   // 72 KB
  const int t  = threadIdx.x;
  const int b  = blockIdx.x;
  const int n  = t & (NPER - 1);
  const int ch = __builtin_amdgcn_readfirstlane(t >> 9);  // column half (wave-uniform)

  // 4 edges per thread, node ids packed; v2 accumulators folded at the end
  int epk[4];
  v2f eaccv[4];
#pragma unroll
  for (int i = 0; i < 4; ++i) {
    const size_t e = (size_t)b * EPER + t + i * 1024;
    epk[i] = (edge0[e] & (NPER - 1)) | ((edge1[e] & (NPER - 1)) << 16);
    eaccv[i] = (v2f){0.f, 0.f};
  }

  const float* __restrict__ hrow = h + ((size_t)b * NPER + n) * DDIM;

  for (int jt = 0; jt < NTILE; ++jt) {
    const int j0 = jt * CT;            // tile's first column
    const int jc = j0 + ch * 16;       // this thread's 16 columns (wave-uniform)

    asm volatile("" ::: "memory");     // no hoisting of h loads across tiles

    v2f pa[8], pb[8];
#pragma unroll
    for (int jj = 0; jj < 8; ++jj) {
      pa[jj] = *(const v2f*)(b1 + jc + 2 * jj);   // uniform -> s_load
      pb[jj] = (v2f){0.f, 0.f};
    }

#pragma unroll
    for (int dc = 0; dc < 8; ++dc) {
      const float4* hp = (const float4*)(hrow + dc * 8);
      const float4 h0 = hp[0], h1 = hp[1];
      const float hc[8] = {h0.x, h0.y, h0.z, h0.w, h1.x, h1.y, h1.z, h1.w};
#pragma unroll
      for (int k = 0; k < 8; ++k) {
        const int d = dc * 8 + k;
        const v2f hv2 = {hc[k], hc[k]};
        const v2f* __restrict__ wa = (const v2f*)(W1 + d * HIDDEN + jc);          // s_loads
        const v2f* __restrict__ wb = (const v2f*)(W1 + (DDIM + d) * HIDDEN + jc); // s_loads
#pragma unroll
        for (int jj = 0; jj < 8; ++jj)
          pa[jj] = __builtin_elementwise_fma(hv2, wa[jj], pa[jj]);
#pragma unroll
        for (int jj = 0; jj < 8; ++jj)
          pb[jj] = __builtin_elementwise_fma(hv2, wb[jj], pb[jj]);
      }
    }

    // stage: disjoint 16-col halves of the 32-col row (single phase)
    {
      float* ap = At + n * STR + ch * 16;
      float* bp = Bt + n * STR + ch * 16;
#pragma unroll
      for (int q = 0; q < 4; ++q) {
        float4 s = {pa[2*q].x, pa[2*q].y, pa[2*q+1].x, pa[2*q+1].y};
        ((float4*)ap)[q] = s;
        float4 u = {pb[2*q].x, pb[2*q].y, pb[2*q+1].x, pb[2*q+1].y};
        ((float4*)bp)[q] = u;
      }
    }
    __syncthreads();

    // edge gather over the 32-col tile (packed)
#pragma unroll
    for (int i = 0; i < 4; ++i) {
      const int er = epk[i] & 0xffff;
      const int ec = ((unsigned)epk[i]) >> 16;
      const float4* ar = (const float4*)(At + er * STR);
      const float4* br = (const float4*)(Bt + ec * STR);
      v2f acc = {0.f, 0.f};
#pragma unroll
      for (int q = 0; q < 8; ++q) {
        const float4 a = ar[q], c = br[q];
        const v2f w0 = *(const v2f*)(W2 + j0 + 4 * q);       // uniform -> s_load
        const v2f w1 = *(const v2f*)(W2 + j0 + 4 * q + 2);
        v2f s0 = {a.x + c.x, a.y + c.y};
        v2f s1 = {a.z + c.z, a.w + c.w};
        s0 = __builtin_elementwise_max(s0, (v2f){0.f, 0.f});
        s1 = __builtin_elementwise_max(s1, (v2f){0.f, 0.f});
        acc = __builtin_elementwise_fma(s0, w0, acc);
        acc = __builtin_elementwise_fma(s1, w1, acc);
      }
      eaccv[i] += acc;
    }
    __syncthreads();   // tile consumed before next staging
  }

  const float b2v = b2[0];
#pragma unroll
  for (int i = 0; i < 4; ++i)
    sc_out[(size_t)b * EPER + t + i * 1024] = eaccv[i].x + eaccv[i].y + b2v;
}

// Kernel B: per-graph bitonic sort of (score desc, idx asc) packed u64 keys,
// write causal/spurious edge weights, build node mask from kept edges,
// masked-sum h -> causal_rep. One block per graph.  (R1-verified version.)
__global__ __launch_bounds__(1024) void sort_kernel(
    const float* __restrict__ sc, const int* __restrict__ edge0,
    const int* __restrict__ edge1, const float* __restrict__ h,
    float* __restrict__ out_rep, float* __restrict__ out_cw,
    float* __restrict__ out_sw)
{
  __shared__ unsigned long long keys[EPER];  // 32 KB
  __shared__ int mask[NPER];                 // 2 KB
  __shared__ float red[16 * 64];             // 4 KB
  const int t = threadIdx.x;
  const int b = blockIdx.x;

  if (t < NPER) mask[t] = 0;

  // build keys: ascending u64 order == (score desc, edge idx asc)
#pragma unroll
  for (int i = 0; i < 4; ++i) {
    const int e = t + i * 1024;
    const float s = sc[(size_t)b * EPER + e];
    unsigned u  = __float_as_uint(s);
    unsigned fk = (u & 0x80000000u) ? ~u : (u | 0x80000000u);  // ascending-orderable
    unsigned dk = ~fk;                                          // descending
    keys[e] = ((unsigned long long)dk << 32) | (unsigned)e;
  }

  for (int k = 2; k <= EPER; k <<= 1) {
    for (int j = k >> 1; j > 0; j >>= 1) {
      __syncthreads();
#pragma unroll
      for (int i = 0; i < 4; ++i) {
        const int p = t + i * 1024;
        const int l = p ^ j;
        if (l > p) {
          const unsigned long long a = keys[p], c = keys[l];
          const bool up = ((p & k) == 0);
          if (up ? (a > c) : (a < c)) { keys[p] = c; keys[l] = a; }
        }
      }
    }
  }
  __syncthreads();

  // sorted outputs: positions [0,K) -> causal weights, [K,E) -> -score
#pragma unroll
  for (int i = 0; i < 4; ++i) {
    const int p = t + i * 1024;
    const unsigned long long key = keys[p];
    const unsigned fk = ~(unsigned)(key >> 32);
    const unsigned u  = (fk & 0x80000000u) ? (fk & 0x7fffffffu) : ~fk;  // exact bits back
    const float s = __uint_as_float(u);
    if (p < KKEEP) out_cw[(size_t)b * KKEEP + p] = s;
    else           out_sw[(size_t)b * (EPER - KKEEP) + (p - KKEEP)] = -s;
  }

  // node mask from kept edges (blockDim == KKEEP, so thread t owns position t)
  {
    const int e = (int)(keys[t] & 0xffffffffu);
    const size_t eg = (size_t)b * EPER + e;
    mask[edge0[eg] & (NPER - 1)] = 1;   // same-value LDS races are benign
    mask[edge1[eg] & (NPER - 1)] = 1;
  }
  __syncthreads();

  // masked segment sum: lanes = dims (coalesced h reads), 16 node-groups
  {
    const int d = t & 63, g = t >> 6;
    float s = 0.f;
    for (int nn = g; nn < NPER; nn += 16)
      if (mask[nn]) s += h[((size_t)b * NPER + nn) * DDIM + d];
    red[g * 64 + d] = s;
  }
  __syncthreads();
  if (t < 64) {
    float tot = 0.f;
#pragma unroll
    for (int g = 0; g < 16; ++g) tot += red[g * 64 + t];
    out_rep[(size_t)b * DDIM + t] = tot;
  }
}

extern "C" void kernel_launch(void* const* d_in, const int* in_sizes, int n_in,
                              void* d_out, int out_size, void* d_ws, size_t ws_size,
                              hipStream_t stream) {
  const float* h    = (const float*)d_in[0];
  const float* W1   = (const float*)d_in[1];
  const float* b1   = (const float*)d_in[2];
  const float* W2   = (const float*)d_in[3];
  const float* b2   = (const float*)d_in[4];
  const int*   eidx = (const int*)d_in[5];
  const int* edge0 = eidx;
  const int* edge1 = eidx + (size_t)B_GRAPHS * EPER;

  float* sc = (float*)d_ws;                 // 4 MB scratch for scores

  float* out     = (float*)d_out;
  float* out_rep = out;                                   // 256*64
  float* out_cw  = out + B_GRAPHS * DDIM;                 // 256*1024
  float* out_sw  = out_cw + (size_t)B_GRAPHS * KKEEP;     // 256*3072

  scores_kernel<<<B_GRAPHS, 1024, 0, stream>>>(h, W1, b1, W2, b2, edge0, edge1, sc);
  sort_kernel<<<B_GRAPHS, 1024, 0, stream>>>(sc, edge0, edge1, h, out_rep, out_cw, out_sw);
}

// Round 14
// 406.782 us; speedup vs baseline: 1.0796x; 1.0796x over previous
//
#include <hip/hip_runtime.h>
#include <stdint.h>

#define B_GRAPHS 256
#define NPER     512
#define EPER     4096
#define DDIM     64
#define KKEEP    1024
#define HIDDEN   256
#define CT       8            // hidden columns per tile
#define NTILE    (HIDDEN/CT)  // 32 tiles
#define STR      12           // LDS row stride: 8 cols + 4 pad = 48B, 16B-aligned

typedef unsigned long long u64;

// Kernel A: one 1024-thread block per graph (R6-R9: only one workgroup is
// ever resident per CU -- all overlap must come from within the block).
// SOFTWARE-PIPELINED: iteration jt computes tile jt's projection (VALU +
// W1 s_loads) AND tile jt-1's edge gather (LDS) in the same barrier interval,
// with double-buffered LDS tiles. R10 post-mortem: serial phases cost
// VALU 207K + LDS 164K + 32 barrier drains = 518K cyc/CU; interleaving the
// two independent streams lets the scheduler overlap pipes -> ~max instead
// of sum. One barrier per iteration: write buf[jt&1], read buf[(jt-1)&1];
// buf[jt&1] was last READ in iteration jt-1 (tile jt-2), so the end-of-
// iteration barrier orders the write-after-read hazard.
// W1/W2/b1 in literal scalar form -> s_loads (R12: pointer casts break
// scalarization, 1.7x regression). asm clobber per tile prevents hoisting h
// into a 64-float live set (R1/R3: RA hard-caps 1024-thread kernels at 64
// VGPR and spills ~800MB to scratch). Thread (n=t&511, ch=t>>9) owns 4 of
// the tile's 8 columns -> disjoint partials, no cross-thread reduction.
__global__ __launch_bounds__(1024) void scores_kernel(
    const float* __restrict__ h, const float* __restrict__ W1,
    const float* __restrict__ b1, const float* __restrict__ W2,
    const float* __restrict__ b2, const int* __restrict__ edge0,
    const int* __restrict__ edge1, float* __restrict__ sc_out)
{
  __shared__ __align__(16) float At[2][NPER * STR];   // 2 x 24 KB
  __shared__ __align__(16) float Bt[2][NPER * STR];   // 2 x 24 KB
  const int t  = threadIdx.x;
  const int b  = blockIdx.x;
  const int n  = t & (NPER - 1);
  const int ch = __builtin_amdgcn_readfirstlane(t >> 9);  // column half (wave-uniform)

  int epk[4];
  float eacc[4];
#pragma unroll
  for (int i = 0; i < 4; ++i) {
    const size_t e = (size_t)b * EPER + t + i * 1024;
    epk[i] = (edge0[e] & (NPER - 1)) | ((edge1[e] & (NPER - 1)) << 16);
    eacc[i] = 0.f;
  }

  const float* __restrict__ hrow = h + ((size_t)b * NPER + n) * DDIM;

  for (int jt = 0; jt <= NTILE; ++jt) {
    // ---- produce tile jt into buf[jt&1] (projection: VALU + s_loads) ----
    if (jt < NTILE) {
      const int cur = jt & 1;
      const int jc  = jt * CT + ch * 4;   // this thread's 4 columns

      asm volatile("" ::: "memory");      // no hoisting of h loads across tiles

      float pa[4], pb[4];
#pragma unroll
      for (int jj = 0; jj < 4; ++jj) { pa[jj] = b1[jc + jj]; pb[jj] = 0.f; }

#pragma unroll
      for (int dc = 0; dc < 4; ++dc) {
        const float4* hp = (const float4*)(hrow + dc * 16);
        float4 h0 = hp[0], h1 = hp[1], h2 = hp[2], h3 = hp[3];
        float hc[16];
        hc[0]=h0.x; hc[1]=h0.y; hc[2]=h0.z; hc[3]=h0.w;
        hc[4]=h1.x; hc[5]=h1.y; hc[6]=h1.z; hc[7]=h1.w;
        hc[8]=h2.x; hc[9]=h2.y; hc[10]=h2.z; hc[11]=h2.w;
        hc[12]=h3.x; hc[13]=h3.y; hc[14]=h3.z; hc[15]=h3.w;
#pragma unroll
        for (int k = 0; k < 16; ++k) {
          const int d = dc * 16 + k;
          const float hv = hc[k];
#pragma unroll
          for (int jj = 0; jj < 4; ++jj)
            pa[jj] = fmaf(hv, W1[d * HIDDEN + jc + jj], pa[jj]);          // s_loads
#pragma unroll
          for (int jj = 0; jj < 4; ++jj)
            pb[jj] = fmaf(hv, W1[(DDIM + d) * HIDDEN + jc + jj], pb[jj]); // s_loads
        }
      }
      {
        float4 s = {pa[0], pa[1], pa[2], pa[3]};
        float4 u = {pb[0], pb[1], pb[2], pb[3]};
        *(float4*)(At[cur] + n * STR + ch * 4) = s;   // 16B-aligned
        *(float4*)(Bt[cur] + n * STR + ch * 4) = u;
      }
    }

    // ---- consume tile jt-1 from buf[(jt-1)&1] (gather: LDS) ----
    if (jt >= 1) {
      const int p  = (jt - 1) & 1;
      const int j0 = (jt - 1) * CT;
      float w2r[CT];
#pragma unroll
      for (int jj = 0; jj < CT; ++jj) w2r[jj] = W2[j0 + jj];   // s_loads
#pragma unroll
      for (int i = 0; i < 4; ++i) {
        const int er = epk[i] & 0xffff;
        const int ec = ((unsigned)epk[i]) >> 16;
        const float4* ar = (const float4*)(At[p] + er * STR);
        const float4* br = (const float4*)(Bt[p] + ec * STR);
        const float4 a0 = ar[0], a1 = ar[1];
        const float4 c0 = br[0], c1 = br[1];
        float q = 0.f;
        q = fmaf(fmaxf(a0.x + c0.x, 0.f), w2r[0], q);
        q = fmaf(fmaxf(a0.y + c0.y, 0.f), w2r[1], q);
        q = fmaf(fmaxf(a0.z + c0.z, 0.f), w2r[2], q);
        q = fmaf(fmaxf(a0.w + c0.w, 0.f), w2r[3], q);
        q = fmaf(fmaxf(a1.x + c1.x, 0.f), w2r[4], q);
        q = fmaf(fmaxf(a1.y + c1.y, 0.f), w2r[5], q);
        q = fmaf(fmaxf(a1.z + c1.z, 0.f), w2r[6], q);
        q = fmaf(fmaxf(a1.w + c1.w, 0.f), w2r[7], q);
        eacc[i] += q;
      }
    }

    __syncthreads();   // orders produce(jt) vs consume at jt+1, and protects
                       // buf[jt&1] (last read in iteration jt-1) from next write
  }

  const float b2v = b2[0];
#pragma unroll
  for (int i = 0; i < 4; ++i)
    sc_out[(size_t)b * EPER + t + i * 1024] = eacc[i] + b2v;
}

// Kernel B: per-graph bitonic sort of (score desc, idx asc) packed u64 keys,
// write causal/spurious edge weights, build node mask from kept edges,
// masked-sum h -> causal_rep. One block per graph.  (R1-verified version;
// register/shuffle rewrites ICE this toolchain -- confirmed R2/R13.)
__global__ __launch_bounds__(1024) void sort_kernel(
    const float* __restrict__ sc, const int* __restrict__ edge0,
    const int* __restrict__ edge1, const float* __restrict__ h,
    float* __restrict__ out_rep, float* __restrict__ out_cw,
    float* __restrict__ out_sw)
{
  __shared__ unsigned long long keys[EPER];  // 32 KB
  __shared__ int mask[NPER];                 // 2 KB
  __shared__ float red[16 * 64];             // 4 KB
  const int t = threadIdx.x;
  const int b = blockIdx.x;

  if (t < NPER) mask[t] = 0;

  // build keys: ascending u64 order == (score desc, edge idx asc)
#pragma unroll
  for (int i = 0; i < 4; ++i) {
    const int e = t + i * 1024;
    const float s = sc[(size_t)b * EPER + e];
    unsigned u  = __float_as_uint(s);
    unsigned fk = (u & 0x80000000u) ? ~u : (u | 0x80000000u);  // ascending-orderable
    unsigned dk = ~fk;                                          // descending
    keys[e] = ((unsigned long long)dk << 32) | (unsigned)e;
  }

  for (int k = 2; k <= EPER; k <<= 1) {
    for (int j = k >> 1; j > 0; j >>= 1) {
      __syncthreads();
#pragma unroll
      for (int i = 0; i < 4; ++i) {
        const int p = t + i * 1024;
        const int l = p ^ j;
        if (l > p) {
          const unsigned long long a = keys[p], c = keys[l];
          const bool up = ((p & k) == 0);
          if (up ? (a > c) : (a < c)) { keys[p] = c; keys[l] = a; }
        }
      }
    }
  }
  __syncthreads();

  // sorted outputs: positions [0,K) -> causal weights, [K,E) -> -score
#pragma unroll
  for (int i = 0; i < 4; ++i) {
    const int p = t + i * 1024;
    const unsigned long long key = keys[p];
    const unsigned fk = ~(unsigned)(key >> 32);
    const unsigned u  = (fk & 0x80000000u) ? (fk & 0x7fffffffu) : ~fk;  // exact bits back
    const float s = __uint_as_float(u);
    if (p < KKEEP) out_cw[(size_t)b * KKEEP + p] = s;
    else           out_sw[(size_t)b * (EPER - KKEEP) + (p - KKEEP)] = -s;
  }

  // node mask from kept edges (blockDim == KKEEP, so thread t owns position t)
  {
    const int e = (int)(keys[t] & 0xffffffffu);
    const size_t eg = (size_t)b * EPER + e;
    mask[edge0[eg] & (NPER - 1)] = 1;   // same-value LDS races are benign
    mask[edge1[eg] & (NPER - 1)] = 1;
  }
  __syncthreads();

  // masked segment sum: lanes = dims (coalesced h reads), 16 node-groups
  {
    const int d = t & 63, g = t >> 6;
    float s = 0.f;
    for (int nn = g; nn < NPER; nn += 16)
      if (mask[nn]) s += h[((size_t)b * NPER + nn) * DDIM + d];
    red[g * 64 + d] = s;
  }
  __syncthreads();
  if (t < 64) {
    float tot = 0.f;
#pragma unroll
    for (int g = 0; g < 16; ++g) tot += red[g * 64 + t];
    out_rep[(size_t)b * DDIM + t] = tot;
  }
}

extern "C" void kernel_launch(void* const* d_in, const int* in_sizes, int n_in,
                              void* d_out, int out_size, void* d_ws, size_t ws_size,
                              hipStream_t stream) {
  const float* h    = (const float*)d_in[0];
  const float* W1   = (const float*)d_in[1];
  const float* b1   = (const float*)d_in[2];
  const float* W2   = (const float*)d_in[3];
  const float* b2   = (const float*)d_in[4];
  const int*   eidx = (const int*)d_in[5];
  const int* edge0 = eidx;
  const int* edge1 = eidx + (size_t)B_GRAPHS * EPER;

  float* sc = (float*)d_ws;                 // 4 MB scratch for scores

  float* out     = (float*)d_out;
  float* out_rep = out;                                   // 256*64
  float* out_cw  = out + B_GRAPHS * DDIM;                 // 256*1024
  float* out_sw  = out_cw + (size_t)B_GRAPHS * KKEEP;     // 256*3072

  scores_kernel<<<B_GRAPHS, 1024, 0, stream>>>(h, W1, b1, W2, b2, edge0, edge1, sc);
  sort_kernel<<<B_GRAPHS, 1024, 0, stream>>>(sc, edge0, edge1, h, out_rep, out_cw, out_sw);
}

// Round 15
// 405.314 us; speedup vs baseline: 1.0835x; 1.0036x over previous
//
#include <hip/hip_runtime.h>
#include <stdint.h>

#define B_GRAPHS 256
#define NPER     512
#define EPER     4096
#define DDIM     64
#define KKEEP    1024
#define HIDDEN   256
#define CT       32          // hidden columns per tile
#define NTILE    (HIDDEN/CT) // 8 tiles
#define STR      36          // LDS row stride: 32 cols + 4 pad = 144B, 16B-aligned

typedef unsigned long long u64;

// Kernel A: R10 structure (best measured: ~216us scores) with CT=32: 8 tiles
// -> 16 barriers instead of 32. R12 tested CT=32 confounded with a v2f W1
// pointer-cast that broke s_load scalarization (VMEM-bound, 370us); this is
// the clean test: W1/W2/b1 in literal scalar form -> s_loads.
// One 1024-thread block per graph (R6-R9: only one workgroup is ever resident
// per CU; overlap attempts R7/R8/R9/R11/R14 all regressed -> serial-minimal
// design). Thread (n=t&511, ch=t>>9) computes the full 64-dim dot-product for
// its 16 of the tile's 32 columns; disjoint partials, 1 staging phase,
// 2 barriers/tile. asm clobber stops h-load hoisting into a 64-float live set
// (R1/R3 trap: RA hard-caps 1024-thread kernels at 64 VGPR, spills ~800MB).
__global__ __launch_bounds__(1024) void scores_kernel(
    const float* __restrict__ h, const float* __restrict__ W1,
    const float* __restrict__ b1, const float* __restrict__ W2,
    const float* __restrict__ b2, const int* __restrict__ edge0,
    const int* __restrict__ edge1, float* __restrict__ sc_out)
{
  __shared__ __align__(16) float At[NPER * STR];   // 72 KB
  __shared__ __align__(16) float Bt[NPER * STR];   // 72 KB
  const int t  = threadIdx.x;
  const int b  = blockIdx.x;
  const int n  = t & (NPER - 1);
  const int ch = __builtin_amdgcn_readfirstlane(t >> 9);  // column half (wave-uniform)

  int epk[4];
  float eacc[4];
#pragma unroll
  for (int i = 0; i < 4; ++i) {
    const size_t e = (size_t)b * EPER + t + i * 1024;
    epk[i] = (edge0[e] & (NPER - 1)) | ((edge1[e] & (NPER - 1)) << 16);
    eacc[i] = 0.f;
  }

  const float* __restrict__ hrow = h + ((size_t)b * NPER + n) * DDIM;

  for (int jt = 0; jt < NTILE; ++jt) {
    const int j0 = jt * CT;
    const int jc = j0 + ch * 16;       // this thread's 16 columns (wave-uniform)

    asm volatile("" ::: "memory");     // no hoisting of h loads across tiles

    float pa[16], pb[16];
#pragma unroll
    for (int jj = 0; jj < 16; ++jj) { pa[jj] = b1[jc + jj]; pb[jj] = 0.f; }

#pragma unroll
    for (int dc = 0; dc < 4; ++dc) {
      const float4* hp = (const float4*)(hrow + dc * 16);
      float4 h0 = hp[0], h1 = hp[1], h2 = hp[2], h3 = hp[3];
      float hc[16];
      hc[0]=h0.x; hc[1]=h0.y; hc[2]=h0.z; hc[3]=h0.w;
      hc[4]=h1.x; hc[5]=h1.y; hc[6]=h1.z; hc[7]=h1.w;
      hc[8]=h2.x; hc[9]=h2.y; hc[10]=h2.z; hc[11]=h2.w;
      hc[12]=h3.x; hc[13]=h3.y; hc[14]=h3.z; hc[15]=h3.w;
#pragma unroll
      for (int k = 0; k < 16; ++k) {
        const int d = dc * 16 + k;
        const float hv = hc[k];
#pragma unroll
        for (int jj = 0; jj < 16; ++jj)
          pa[jj] = fmaf(hv, W1[d * HIDDEN + jc + jj], pa[jj]);          // s_loads
#pragma unroll
        for (int jj = 0; jj < 16; ++jj)
          pb[jj] = fmaf(hv, W1[(DDIM + d) * HIDDEN + jc + jj], pb[jj]); // s_loads
      }
    }

    // stage: disjoint 16-col halves of the 32-col row (single phase)
    {
      float* ap = At + n * STR + ch * 16;
      float* bp = Bt + n * STR + ch * 16;
#pragma unroll
      for (int q = 0; q < 4; ++q) {
        float4 s = {pa[4*q+0], pa[4*q+1], pa[4*q+2], pa[4*q+3]};
        ((float4*)ap)[q] = s;
      }
#pragma unroll
      for (int q = 0; q < 4; ++q) {
        float4 u = {pb[4*q+0], pb[4*q+1], pb[4*q+2], pb[4*q+3]};
        ((float4*)bp)[q] = u;
      }
    }
    __syncthreads();

    // edge gather over the 32-col tile
    float w2r[CT];
#pragma unroll
    for (int jj = 0; jj < CT; ++jj) w2r[jj] = W2[j0 + jj];   // uniform -> SGPRs

#pragma unroll
    for (int i = 0; i < 4; ++i) {
      const int er = epk[i] & 0xffff;
      const int ec = ((unsigned)epk[i]) >> 16;
      const float4* ar = (const float4*)(At + er * STR);
      const float4* br = (const float4*)(Bt + ec * STR);
      float p = 0.f;
#pragma unroll
      for (int q = 0; q < 8; ++q) {
        const float4 a = ar[q], c = br[q];
        p = fmaf(fmaxf(a.x + c.x, 0.f), w2r[4*q+0], p);
        p = fmaf(fmaxf(a.y + c.y, 0.f), w2r[4*q+1], p);
        p = fmaf(fmaxf(a.z + c.z, 0.f), w2r[4*q+2], p);
        p = fmaf(fmaxf(a.w + c.w, 0.f), w2r[4*q+3], p);
      }
      eacc[i] += p;
    }
    __syncthreads();   // tile consumed before next staging
  }

  const float b2v = b2[0];
#pragma unroll
  for (int i = 0; i < 4; ++i)
    sc_out[(size_t)b * EPER + t + i * 1024] = eacc[i] + b2v;
}

// Kernel B: per-graph bitonic sort of (score desc, idx asc) packed u64 keys,
// write causal/spurious edge weights, build node mask from kept edges,
// masked-sum h -> causal_rep. One block per graph.  (R1-verified version;
// register/shuffle rewrites ICE this toolchain -- confirmed R2/R13.)
__global__ __launch_bounds__(1024) void sort_kernel(
    const float* __restrict__ sc, const int* __restrict__ edge0,
    const int* __restrict__ edge1, const float* __restrict__ h,
    float* __restrict__ out_rep, float* __restrict__ out_cw,
    float* __restrict__ out_sw)
{
  __shared__ unsigned long long keys[EPER];  // 32 KB
  __shared__ int mask[NPER];                 // 2 KB
  __shared__ float red[16 * 64];             // 4 KB
  const int t = threadIdx.x;
  const int b = blockIdx.x;

  if (t < NPER) mask[t] = 0;

  // build keys: ascending u64 order == (score desc, edge idx asc)
#pragma unroll
  for (int i = 0; i < 4; ++i) {
    const int e = t + i * 1024;
    const float s = sc[(size_t)b * EPER + e];
    unsigned u  = __float_as_uint(s);
    unsigned fk = (u & 0x80000000u) ? ~u : (u | 0x80000000u);  // ascending-orderable
    unsigned dk = ~fk;                                          // descending
    keys[e] = ((unsigned long long)dk << 32) | (unsigned)e;
  }

  for (int k = 2; k <= EPER; k <<= 1) {
    for (int j = k >> 1; j > 0; j >>= 1) {
      __syncthreads();
#pragma unroll
      for (int i = 0; i < 4; ++i) {
        const int p = t + i * 1024;
        const int l = p ^ j;
        if (l > p) {
          const unsigned long long a = keys[p], c = keys[l];
          const bool up = ((p & k) == 0);
          if (up ? (a > c) : (a < c)) { keys[p] = c; keys[l] = a; }
        }
      }
    }
  }
  __syncthreads();

  // sorted outputs: positions [0,K) -> causal weights, [K,E) -> -score
#pragma unroll
  for (int i = 0; i < 4; ++i) {
    const int p = t + i * 1024;
    const unsigned long long key = keys[p];
    const unsigned fk = ~(unsigned)(key >> 32);
    const unsigned u  = (fk & 0x80000000u) ? (fk & 0x7fffffffu) : ~fk;  // exact bits back
    const float s = __uint_as_float(u);
    if (p < KKEEP) out_cw[(size_t)b * KKEEP + p] = s;
    else           out_sw[(size_t)b * (EPER - KKEEP) + (p - KKEEP)] = -s;
  }

  // node mask from kept edges (blockDim == KKEEP, so thread t owns position t)
  {
    const int e = (int)(keys[t] & 0xffffffffu);
    const size_t eg = (size_t)b * EPER + e;
    mask[edge0[eg] & (NPER - 1)] = 1;   // same-value LDS races are benign
    mask[edge1[eg] & (NPER - 1)] = 1;
  }
  __syncthreads();

  // masked segment sum: lanes = dims (coalesced h reads), 16 node-groups
  {
    const int d = t & 63, g = t >> 6;
    float s = 0.f;
    for (int nn = g; nn < NPER; nn += 16)
      if (mask[nn]) s += h[((size_t)b * NPER + nn) * DDIM + d];
    red[g * 64 + d] = s;
  }
  __syncthreads();
  if (t < 64) {
    float tot = 0.f;
#pragma unroll
    for (int g = 0; g < 16; ++g) tot += red[g * 64 + t];
    out_rep[(size_t)b * DDIM + t] = tot;
  }
}

extern "C" void kernel_launch(void* const* d_in, const int* in_sizes, int n_in,
                              void* d_out, int out_size, void* d_ws, size_t ws_size,
                              hipStream_t stream) {
  const float* h    = (const float*)d_in[0];
  const float* W1   = (const float*)d_in[1];
  const float* b1   = (const float*)d_in[2];
  const float* W2   = (const float*)d_in[3];
  const float* b2   = (const float*)d_in[4];
  const int*   eidx = (const int*)d_in[5];
  const int* edge0 = eidx;
  const int* edge1 = eidx + (size_t)B_GRAPHS * EPER;

  float* sc = (float*)d_ws;                 // 4 MB scratch for scores

  float* out     = (float*)d_out;
  float* out_rep = out;                                   // 256*64
  float* out_cw  = out + B_GRAPHS * DDIM;                 // 256*1024
  float* out_sw  = out_cw + (size_t)B_GRAPHS * KKEEP;     // 256*3072

  scores_kernel<<<B_GRAPHS, 1024, 0, stream>>>(h, W1, b1, W2, b2, edge0, edge1, sc);
  sort_kernel<<<B_GRAPHS, 1024, 0, stream>>>(sc, edge0, edge1, h, out_rep, out_cw, out_sw);
}